// Round 1
// baseline (311.324 us; speedup 1.0000x reference)
//
#include <hip/hip_runtime.h>

// out[b,f] = x0[b,f] * dot(x[b,:], w) + bias[f] + x[b,f]
// B = 16384 rows, F = 2048 cols, fp32 throughout.
//
// Wave-per-row, barrier-free version. F/4 = 512 float4 slots per row =
// 64 lanes x 8 slots, so ONE 64-lane wave owns a full row:
//   - 8 float4 of x and 8 of x0 are loaded into registers up front
//     (16 coalesced 1 KiB loads in flight per wave -> deep MLP),
//   - the dot is reduced with a 6-step __shfl_xor butterfly entirely
//     in-wave (no LDS, no __syncthreads on any row's critical path),
//   - epilogue reuses the register-resident x row.
// A 256-thread block = 4 independent rows; waves never wait on each other,
// so the VMEM pipe stays fed while any one wave sits in its reduce.
// w/bias are 8 KiB broadcasts (L1-resident), streamed transiently.

#define F_DIM 2048
#define SLOTS 8  // float4 slots per lane: (F_DIM/4)/64

__global__ __launch_bounds__(256) void cross_row_kernel(
    const float* __restrict__ x0,
    const float* __restrict__ x,
    const float* __restrict__ w,
    const float* __restrict__ bias,
    float* __restrict__ out)
{
    const int wave = threadIdx.x >> 6;
    const int lane = threadIdx.x & 63;
    const long long b = (long long)blockIdx.x * 4 + wave;
    const long long row = b * (long long)F_DIM;

    const float4* __restrict__ x4  = (const float4*)(x  + row);
    const float4* __restrict__ x04 = (const float4*)(x0 + row);
    const float4* __restrict__ w4  = (const float4*)w;
    const float4* __restrict__ bi4 = (const float4*)bias;
    float4*       __restrict__ o4  = (float4*)(out + row);

    // Issue all x loads (needed first, for the dot), then all x0 loads
    // (needed last, but in flight across the reduce). Fully unrolled ->
    // static register indexing (no scratch).
    float4 xr[SLOTS], x0r[SLOTS];
    #pragma unroll
    for (int i = 0; i < SLOTS; ++i) xr[i]  = x4 [lane + 64 * i];
    #pragma unroll
    for (int i = 0; i < SLOTS; ++i) x0r[i] = x04[lane + 64 * i];

    // Per-lane partial dot over 32 elements; w streamed (L1 hit).
    float partial = 0.0f;
    #pragma unroll
    for (int i = 0; i < SLOTS; ++i) {
        const float4 wv = w4[lane + 64 * i];
        partial += xr[i].x * wv.x + xr[i].y * wv.y
                 + xr[i].z * wv.z + xr[i].w * wv.w;
    }

    // 64-lane butterfly: every lane ends with the full row dot.
    #pragma unroll
    for (int off = 32; off > 0; off >>= 1)
        partial += __shfl_xor(partial, off, 64);
    const float dot = partial;

    // Epilogue: x0*dot + bias + x, register-resident x reused.
    #pragma unroll
    for (int i = 0; i < SLOTS; ++i) {
        const float4 bv = bi4[lane + 64 * i];
        float4 o;
        o.x = x0r[i].x * dot + (bv.x + xr[i].x);
        o.y = x0r[i].y * dot + (bv.y + xr[i].y);
        o.z = x0r[i].z * dot + (bv.z + xr[i].z);
        o.w = x0r[i].w * dot + (bv.w + xr[i].w);
        o4[lane + 64 * i] = o;
    }
}

extern "C" void kernel_launch(void* const* d_in, const int* in_sizes, int n_in,
                              void* d_out, int out_size, void* d_ws, size_t ws_size,
                              hipStream_t stream) {
    const float* x0   = (const float*)d_in[0];
    const float* x    = (const float*)d_in[1];
    const float* w    = (const float*)d_in[2];
    const float* bias = (const float*)d_in[3];
    float* out = (float*)d_out;

    const int B = in_sizes[0] / F_DIM;  // 16384
    cross_row_kernel<<<B / 4, 256, 0, stream>>>(x0, x, w, bias, out);
}

// Round 3
// 307.713 us; speedup vs baseline: 1.0117x; 1.0117x over previous
//
#include <hip/hip_runtime.h>

// out[b,f] = x0[b,f] * dot(x[b,:], w) + bias[f] + x[b,f]
// B = 16384 rows, F = 2048 cols, fp32 throughout.
//
// Round 3 = round 2 with the compile fix: __builtin_nontemporal_* needs a
// NATIVE clang vector type, not HIP's float4 struct. Using
// ext_vector_type(4) float everywhere (same dwordx4 codegen).
//
// Structure (unchanged from round-2 intent):
//   - 4 rows per wave: w and bias (8 KiB each, per-row-invariant) loaded
//     ONCE per wave into registers (amortize 40% of per-row VMEM instrs).
//   - 1-deep cross-row pipeline: row r+1's x/x0 loads issue before row r's
//     reduce, so the dot's vmcnt wait always covers useful HBM traffic.
//   - x0 read + out write are NONTEMPORAL: out doesn't allocate/thrash L3,
//     x0 streams, x gets to own L3 residency (lower mean read latency).
// Zero LDS, zero __syncthreads.

#define F_DIM 2048
#define SLOTS 8   // float4 slots per lane: (F_DIM/4)/64
#define ROWS  4   // rows processed per wave

typedef float f4 __attribute__((ext_vector_type(4)));

__global__ __launch_bounds__(256) void cross_row_kernel(
    const float* __restrict__ x0,
    const float* __restrict__ x,
    const float* __restrict__ w,
    const float* __restrict__ bias,
    float* __restrict__ out)
{
    const int wave = threadIdx.x >> 6;
    const int lane = threadIdx.x & 63;
    const long long wid  = (long long)blockIdx.x * 4 + wave;
    const long long row0 = wid * ROWS;

    const f4* __restrict__ w4  = (const f4*)w;
    const f4* __restrict__ bi4 = (const f4*)bias;

    // Per-wave invariants: full w and bias rows in registers.
    f4 wr[SLOTS], br[SLOTS];
    #pragma unroll
    for (int i = 0; i < SLOTS; ++i) wr[i] = w4 [lane + 64 * i];
    #pragma unroll
    for (int i = 0; i < SLOTS; ++i) br[i] = bi4[lane + 64 * i];

    const f4* __restrict__ xbase  = (const f4*)(x  + row0 * F_DIM);
    const f4* __restrict__ x0base = (const f4*)(x0 + row0 * F_DIM);
    f4*       __restrict__ obase  = (f4*)(out + row0 * F_DIM);
    const int F4 = F_DIM / 4;  // 512 f4 per row

    f4 xa[SLOTS], x0a[SLOTS];   // current row
    f4 xb[SLOTS], x0b[SLOTS];   // prefetched next row

    // Prologue: row 0 in flight.
    #pragma unroll
    for (int i = 0; i < SLOTS; ++i) xa[i] = xbase[lane + 64 * i];
    #pragma unroll
    for (int i = 0; i < SLOTS; ++i)
        x0a[i] = __builtin_nontemporal_load(&x0base[lane + 64 * i]);

    #pragma unroll
    for (int r = 0; r < ROWS; ++r) {
        // Prefetch row r+1 BEFORE the reduce.
        if (r + 1 < ROWS) {
            const f4* __restrict__ xn  = xbase  + (r + 1) * F4;
            const f4* __restrict__ x0n = x0base + (r + 1) * F4;
            #pragma unroll
            for (int i = 0; i < SLOTS; ++i) xb[i] = xn[lane + 64 * i];
            #pragma unroll
            for (int i = 0; i < SLOTS; ++i)
                x0b[i] = __builtin_nontemporal_load(&x0n[lane + 64 * i]);
        }

        // Per-lane partial dot (32 elements), then 64-lane butterfly.
        float partial = 0.0f;
        #pragma unroll
        for (int i = 0; i < SLOTS; ++i)
            partial += xa[i][0] * wr[i][0] + xa[i][1] * wr[i][1]
                     + xa[i][2] * wr[i][2] + xa[i][3] * wr[i][3];
        #pragma unroll
        for (int off = 32; off > 0; off >>= 1)
            partial += __shfl_xor(partial, off, 64);
        const float dot = partial;

        // Epilogue: x0*dot + bias + x, streamed out nontemporally.
        f4* __restrict__ o = obase + r * F4;
        #pragma unroll
        for (int i = 0; i < SLOTS; ++i) {
            f4 ov;
            ov[0] = x0a[i][0] * dot + (br[i][0] + xa[i][0]);
            ov[1] = x0a[i][1] * dot + (br[i][1] + xa[i][1]);
            ov[2] = x0a[i][2] * dot + (br[i][2] + xa[i][2]);
            ov[3] = x0a[i][3] * dot + (br[i][3] + xa[i][3]);
            __builtin_nontemporal_store(ov, &o[lane + 64 * i]);
        }

        // Rotate pipeline registers (statically unrolled -> pure renaming).
        #pragma unroll
        for (int i = 0; i < SLOTS; ++i) { xa[i] = xb[i]; x0a[i] = x0b[i]; }
    }
}

extern "C" void kernel_launch(void* const* d_in, const int* in_sizes, int n_in,
                              void* d_out, int out_size, void* d_ws, size_t ws_size,
                              hipStream_t stream) {
    const float* x0   = (const float*)d_in[0];
    const float* x    = (const float*)d_in[1];
    const float* w    = (const float*)d_in[2];
    const float* bias = (const float*)d_in[3];
    float* out = (float*)d_out;

    const int B = in_sizes[0] / F_DIM;          // 16384 rows
    const int blocks = B / (4 * ROWS);          // 4 waves/block * ROWS rows/wave
    cross_row_kernel<<<blocks, 256, 0, stream>>>(x0, x, w, bias, out);
}